// Round 12
// baseline (86.095 us; speedup 1.0000x reference)
//
#include <hip/hip_runtime.h>
#include <hip/hip_bf16.h>

#define BB   16
#define EMB  768
#define CIN  64
#define COUT 64
#define HH   112
#define WW   112
#define HID  192
#define TOTAL 36864                 // COUT*CIN*9
#define KSZ  576                    // CIN*9
#define PW   114                    // padded H/W
#define CELL 128                    // bytes per P cell: 64 ci * 2B
#define ROWB (PW * CELL)            // 14592 B per padded P row
#define CELLH 64                    // bytes per LDS cell: 32 ci (one half)
#define LROW (PW * CELLH)           // 7296 B per LDS row
#define NCHUNK (6 * PW * 4)         // 2736 16-B chunks per half-stage

typedef short bf16x8 __attribute__((ext_vector_type(8)));
typedef float f32x4  __attribute__((ext_vector_type(4)));
typedef int   i32x4  __attribute__((ext_vector_type(4)));

static __device__ __forceinline__ unsigned short f2bf(float f) {
    unsigned u = __float_as_uint(f);
    u += 0x7FFF + ((u >> 16) & 1);          // RNE
    return (unsigned short)(u >> 16);
}

static __device__ __forceinline__ bf16x8 pack8(const float* v) {
    bf16x8 r;
    #pragma unroll
    for (int j = 0; j < 8; ++j) r[j] = (short)f2bf(v[j]);
    return r;
}

#define GLOAD_LDS16(g, l) \
    __builtin_amdgcn_global_load_lds((const __attribute__((address_space(1))) void*)(g), \
                                     (__attribute__((address_space(3))) void*)(l), 16, 0, 0)

// ---- K1: prepass (blocks 0..1791) + halo (1792..1823) + mlp1 (1824..2015) ----
__global__ __launch_bounds__(256) void pre_mlp1(const float* __restrict__ feat,
                                                unsigned short* __restrict__ P,
                                                const float* __restrict__ cls,
                                                const float* __restrict__ W1,
                                                const float* __restrict__ b1,
                                                float* __restrict__ h) {
    __shared__ float smem[EMB + 16 * 17];
    const int bid = blockIdx.x;
    const int tid = threadIdx.x;

    if (bid < HH * BB) {
        // prepass data row: in-register NCHW->NHWC bf16
        const int b = bid & 15;
        const int y = bid >> 4;                 // image row 0..111
        unsigned short* Prow = P + ((size_t)b * PW + y + 1) * (PW * 64);
        if (tid < 16) {                         // zero x-halo cells 0 and 113
            const int cell = (tid >> 3) ? (PW - 1) : 0;
            *(i32x4*)((char*)Prow + cell * CELL + (tid & 7) * 16) = (i32x4){0, 0, 0, 0};
        }
        const int o = tid >> 5;                 // ci octet 0..7
        const int q = tid & 31;                 // px quad, active < 28
        if (q < 28) {
            const float* fb = feat + (((size_t)b * CIN + o * 8) * HH + y) * WW + 4 * q;
            f32x4 v[8];
            #pragma unroll
            for (int j = 0; j < 8; ++j) v[j] = *(const f32x4*)(fb + (size_t)j * (HH * WW));
            #pragma unroll
            for (int i = 0; i < 4; ++i) {
                unsigned short w[8];
                #pragma unroll
                for (int j = 0; j < 8; ++j) w[j] = f2bf(v[j][i]);
                *(bf16x8*)(Prow + (size_t)(4 * q + i + 1) * 64 + o * 8) = *(bf16x8*)w;
            }
        }
    } else if (bid < HH * BB + 32) {
        // halo rows (py = 0, 113)
        const int idx = bid - HH * BB;
        const int b = idx & 15;
        unsigned short* Prow = P + ((size_t)b * PW + ((idx >> 4) ? (PW - 1) : 0)) * (PW * 64);
        #pragma unroll
        for (int k = 0; k < 4; ++k) {
            const int i = tid + 256 * k;
            if (i < 912) ((i32x4*)Prow)[i] = (i32x4){0, 0, 0, 0};
        }
    } else {
        // mlp1: h = relu(cls @ W1 + b1)
        float* xs  = smem;
        float* red = smem + EMB;
        const int idx = bid - (HH * BB + 32);   // 0..191
        const int b   = idx / 12;
        const int jg  = idx - 12 * b;
        for (int i = tid; i < EMB; i += 256) xs[i] = cls[b * EMB + i];
        __syncthreads();
        const int j16 = tid & 15;
        const int kq  = tid >> 4;
        const int j   = jg * 16 + j16;
        float acc = 0.f;
        #pragma unroll
        for (int k = kq * 48; k < kq * 48 + 48; ++k) acc += xs[k] * W1[k * HID + j];
        red[j16 * 17 + kq] = acc;
        __syncthreads();
        if (tid < 16) {
            float s = b1[jg * 16 + tid];
            #pragma unroll
            for (int q = 0; q < 16; ++q) s += red[tid * 17 + q];
            h[b * HID + jg * 16 + tid] = fmaxf(s, 0.f);
        }
    }
}

// ---- K2: MFMA GEMM  params = tanh(h @ W2 + b2) (+ identity at center tap) ----
__global__ __launch_bounds__(256) void mlp2_kernel(const float* __restrict__ h,
                                                   const float* __restrict__ W2,
                                                   const float* __restrict__ b2,
                                                   unsigned short* __restrict__ Ag) {
    __shared__ float hs[16 * 193];
    const int tid = threadIdx.x;
    for (int i = tid; i < BB * HID; i += 256) {
        const int bb = i / HID;
        hs[bb * 193 + (i - bb * HID)] = h[i];
    }
    __syncthreads();
    const int wave = tid >> 6;
    const int lane = tid & 63;
    const int lg   = lane >> 4;
    const int ln   = lane & 15;
    const int t0   = (blockIdx.x * 4 + wave) * 16;

    bf16x8 a6[6];
    #pragma unroll
    for (int kk = 0; kk < 6; ++kk) {
        float v[8];
        #pragma unroll
        for (int j = 0; j < 8; ++j) v[j] = hs[ln * 193 + kk * 32 + lg * 8 + j];
        a6[kk] = pack8(v);
    }

    f32x4 acc = (f32x4){0.f, 0.f, 0.f, 0.f};
    #pragma unroll
    for (int kk = 0; kk < 6; ++kk) {
        float w[8];
        #pragma unroll
        for (int j = 0; j < 8; ++j)
            w[j] = W2[(size_t)(kk * 32 + lg * 8 + j) * TOTAL + t0 + ln];
        acc = __builtin_amdgcn_mfma_f32_16x16x32_bf16(a6[kk], pack8(w), acc, 0, 0, 0);
    }

    const int t    = t0 + ln;
    const float bias = b2[t];
    const int co  = t / KSZ;
    const int rem = t - co * KSZ;
    const int ci  = rem / 9;
    const int p9  = rem - ci * 9;
    const float idv = (p9 == 4 && co == ci) ? 1.f : 0.f;
    unsigned short* pA = Ag + (size_t)(p9 * 64 + co) * 64 + ci;
    #pragma unroll
    for (int rg = 0; rg < 4; ++rg) {
        const int bi = lg * 4 + rg;
        pA[(size_t)bi * TOTAL] = f2bf(tanhf(acc[rg] + bias) + idv);
    }
}

// -------- K3: conv MFMA implicit GEMM, 4-row strips, wave = 1 row x 64 co --------
// 448 blocks = 16b x 28 strips. LDS: 6 rows x 114 cells x 64 B (one 32-ci half),
// 43776 B -> 3 blocks/CU. ci processed as 2 serial halves re-staged into same LDS.
// Slice swizzle (4 slices of 16 B): slot = g ^ (cell&3); gload_lds linear dest with
// inverse-swizzled source. Each ds_read_b128 feeds 4 MFMAs (4 co-tiles).
__global__ __launch_bounds__(256, 3) void conv_kernel(const unsigned short* __restrict__ Ag,
                                                      const unsigned short* __restrict__ P,
                                                      float* __restrict__ out) {
    __shared__ __align__(16) char lds[6 * LROW];    // 43776 B
    const int tid = threadIdx.x;
    // XCD-chunked swizzle: 56 consecutive logical blocks (= 2 batches) per XCD
    const int bid   = (blockIdx.x & 7) * 56 + (blockIdx.x >> 3);
    const int b     = bid / 28;
    const int strip = bid - b * 28;
    const int y0    = strip * 4;

    const int wave = tid >> 6;                      // output row r = wave
    const int lane = tid & 63;
    const int lg   = lane >> 4;
    const int ln   = lane & 15;

    const unsigned short* Ab = Ag + (size_t)b * 9 * 4096;
    const char* Pb = (const char*)P + ((size_t)b * PW + y0) * ROWB;   // padded rows y0..y0+5

    f32x4 acc[4][7];
    #pragma unroll
    for (int ct = 0; ct < 4; ++ct)
        #pragma unroll
        for (int t = 0; t < 7; ++t) acc[ct][t] = (f32x4){0.f, 0.f, 0.f, 0.f};

    #pragma unroll
    for (int h = 0; h < 2; ++h) {
        // ---- stage half h: 6 rows x 114 cells x 64 B, linear LDS dest ----
        if (h) __syncthreads();                      // half0 compute done before overwrite
        #pragma unroll
        for (int k = 0; k < 11; ++k) {
            const int i = k * 256 + tid;             // chunk 0..2735
            if (i < NCHUNK) {
                const int s    = i / (PW * 4);
                const int rem  = i - s * (PW * 4);
                const int cell = rem >> 2;
                const int sl   = rem & 3;
                const int g    = sl ^ (cell & 3);    // inverse swizzle on source
                GLOAD_LDS16(Pb + (size_t)s * ROWB + cell * CELL + h * 64 + g * 16,
                            lds + (size_t)i * 16);
            }
        }
        asm volatile("s_waitcnt vmcnt(0)" ::: "memory");
        __builtin_amdgcn_s_barrier();
        __builtin_amdgcn_sched_barrier(0);

        // ---- compute half h: per p9, 7 ds_reads, each feeding 4 MFMAs ----
        #pragma unroll
        for (int p9 = 0; p9 < 9; ++p9) {
            const int kh = p9 / 3, kw = p9 - 3 * kh;
            // A-fragments for 4 co-tiles (this half's 32 ci)
            bf16x8 af[4];
            #pragma unroll
            for (int ct = 0; ct < 4; ++ct)
                af[ct] = *(const bf16x8*)(Ab + (size_t)(p9 * 64 + ct * 16 + ln) * 64
                                          + h * 32 + lg * 8);
            const char* lbase = lds + (wave + kh) * LROW;
            #pragma unroll
            for (int t = 0; t < 7; ++t) {
                const int cell = ln + kw + 16 * t;
                const int sl   = lg ^ (cell & 3);
                const bf16x8 bf = *(const bf16x8*)(lbase + cell * CELLH + sl * 16);
                #pragma unroll
                for (int ct = 0; ct < 4; ++ct)
                    acc[ct][t] = __builtin_amdgcn_mfma_f32_16x16x32_bf16(af[ct], bf, acc[ct][t], 0, 0, 0);
            }
        }
    }

    // ---- epilogue: pure stores (residual folded into A) ----
    const int y = y0 + wave;
    float* ob = out + (((size_t)b * COUT + lg * 4) * HH + y) * WW + ln;
    #pragma unroll
    for (int ct = 0; ct < 4; ++ct)
        #pragma unroll
        for (int t = 0; t < 7; ++t)
            #pragma unroll
            for (int rg = 0; rg < 4; ++rg)
                ob[((size_t)(ct * 16 + rg)) * HH * WW + t * 16] = acc[ct][t][rg];
}

extern "C" void kernel_launch(void* const* d_in, const int* in_sizes, int n_in,
                              void* d_out, int out_size, void* d_ws, size_t ws_size,
                              hipStream_t stream) {
    const float* cls      = (const float*)d_in[0];
    const float* features = (const float*)d_in[1];
    const float* W1       = (const float*)d_in[2];
    const float* b1       = (const float*)d_in[3];
    const float* W2       = (const float*)d_in[4];
    const float* b2       = (const float*)d_in[5];
    float* out = (float*)d_out;

    float*          h  = (float*)d_ws;                       // 12 KB
    unsigned short* Ag = (unsigned short*)(h + BB * HID);    // 1.18 MB bf16 A[b][p9][co][ci]
    unsigned short* P  = Ag + (size_t)BB * 9 * 4096;         // 26.6 MB padded NHWC bf16

    pre_mlp1<<<HH * BB + 32 + 192, 256, 0, stream>>>(features, P, cls, W1, b1, h);
    mlp2_kernel<<<TOTAL / 64, 256, 0, stream>>>(h, W2, b2, Ag);
    conv_kernel<<<448, 256, 0, stream>>>(Ag, P, out);
}

// Round 13
// 67.401 us; speedup vs baseline: 1.2774x; 1.2774x over previous
//
#include <hip/hip_runtime.h>
#include <hip/hip_bf16.h>

#define BB   16
#define EMB  768
#define CIN  64
#define COUT 64
#define HH   112
#define WW   112
#define HID  192
#define TOTAL 36864                 // COUT*CIN*9
#define KSZ  576                    // CIN*9
#define PW   114                    // padded H/W
#define CELLB 64                    // bytes per P cell: 32 ci * 2B (split-plane)
#define LROWB (PW * CELLB)          // 7296 B per padded plane-row
#define NCH  (4 * PW * 4)           // 1824 16-B chunks per 4-row half-stage

typedef short bf16x8 __attribute__((ext_vector_type(8)));
typedef float f32x4  __attribute__((ext_vector_type(4)));
typedef int   i32x4  __attribute__((ext_vector_type(4)));

static __device__ __forceinline__ unsigned short f2bf(float f) {
    unsigned u = __float_as_uint(f);
    u += 0x7FFF + ((u >> 16) & 1);          // RNE
    return (unsigned short)(u >> 16);
}

static __device__ __forceinline__ bf16x8 pack8(const float* v) {
    bf16x8 r;
    #pragma unroll
    for (int j = 0; j < 8; ++j) r[j] = (short)f2bf(v[j]);
    return r;
}

#define GLOAD_LDS16(g, l) \
    __builtin_amdgcn_global_load_lds((const __attribute__((address_space(1))) void*)(g), \
                                     (__attribute__((address_space(3))) void*)(l), 16, 0, 0)

// ---- K1: mlp1  h = relu(cls @ W1 + b1).  192 blocks = 16b x 12jg ----
__global__ __launch_bounds__(256) void mlp1_kernel(const float* __restrict__ cls,
                                                   const float* __restrict__ W1,
                                                   const float* __restrict__ b1,
                                                   float* __restrict__ h) {
    __shared__ float xs[EMB];
    __shared__ float red[16][17];
    const int b   = blockIdx.x / 12;
    const int jg  = blockIdx.x - 12 * b;
    const int tid = threadIdx.x;
    for (int i = tid; i < EMB; i += 256) xs[i] = cls[b * EMB + i];
    __syncthreads();
    const int j16 = tid & 15;
    const int kq  = tid >> 4;
    const int j   = jg * 16 + j16;
    float acc = 0.f;
    #pragma unroll
    for (int k = kq * 48; k < kq * 48 + 48; ++k) acc += xs[k] * W1[k * HID + j];
    red[j16][kq] = acc;
    __syncthreads();
    if (tid < 16) {
        float s = b1[jg * 16 + tid];
        #pragma unroll
        for (int q = 0; q < 16; ++q) s += red[tid][q];
        h[b * HID + jg * 16 + tid] = fmaxf(s, 0.f);
    }
}

// ---- K2: fused prepass (split-plane P) + mlp2 MFMA GEMM ----
// blocks 0..1791: data rows; 1792..1823: halo rows; 1824..2399: mlp2 tiles.
// P layout: [b][half][py][px][32ci], plane-row stride LROWB.
__global__ __launch_bounds__(256) void pre_mlp2(const float* __restrict__ feat,
                                                unsigned short* __restrict__ P,
                                                const float* __restrict__ h,
                                                const float* __restrict__ W2,
                                                const float* __restrict__ b2,
                                                unsigned short* __restrict__ Ag) {
    __shared__ float hs[16 * 193];
    const int bid = blockIdx.x;
    const int tid = threadIdx.x;

    if (bid < HH * BB) {
        // ---------------- prepass data row ----------------
        const int b = bid & 15;
        const int y = bid >> 4;                 // image row 0..111
        if (tid < 16) {                         // zero x-halo cells 0,113 both planes
            const int p    = tid >> 3;
            const int cell = ((tid >> 2) & 1) ? (PW - 1) : 0;
            const int sl   = tid & 3;
            char* Prow = (char*)P + ((size_t)(b * 2 + p) * PW + y + 1) * LROWB;
            *(i32x4*)(Prow + cell * CELLB + sl * 16) = (i32x4){0, 0, 0, 0};
        }
        const int o  = tid >> 5;                // ci octet 0..7
        const int p  = o >> 2;                  // plane (ci half)
        const int oo = o & 3;                   // octet within plane
        const int q  = tid & 31;                // px quad, active < 28
        if (q < 28) {
            const float* fb = feat + (((size_t)b * CIN + o * 8) * HH + y) * WW + 4 * q;
            unsigned short* Prow = P + ((size_t)(b * 2 + p) * PW + y + 1) * (PW * 32);
            f32x4 v[8];
            #pragma unroll
            for (int j = 0; j < 8; ++j) v[j] = *(const f32x4*)(fb + (size_t)j * (HH * WW));
            #pragma unroll
            for (int i = 0; i < 4; ++i) {
                unsigned short w[8];
                #pragma unroll
                for (int j = 0; j < 8; ++j) w[j] = f2bf(v[j][i]);
                *(bf16x8*)(Prow + (size_t)(4 * q + i + 1) * 32 + oo * 8) = *(bf16x8*)w;
            }
        }
    } else if (bid < HH * BB + 32) {
        // ---------------- halo rows (py = 0, 113), both planes ----------------
        const int idx = bid - HH * BB;
        const int b   = idx & 15;
        const int py  = (idx >> 4) ? (PW - 1) : 0;
        #pragma unroll
        for (int k = 0; k < 4; ++k) {
            const int i = tid + 256 * k;        // 0..911 = 2 planes x 456 chunks
            if (i < 912) {
                const int p = i / 456, j = i - p * 456;
                char* Prow = (char*)P + ((size_t)(b * 2 + p) * PW + py) * LROWB;
                ((i32x4*)Prow)[j] = (i32x4){0, 0, 0, 0};
            }
        }
    } else {
        // ---------------- mlp2: params = tanh(h @ W2 + b2) + center identity ----------------
        const int blk = bid - (HH * BB + 32);   // 0..575
        for (int i = tid; i < BB * HID; i += 256) {
            const int bb = i / HID;
            hs[bb * 193 + (i - bb * HID)] = h[i];
        }
        __syncthreads();
        const int wave = tid >> 6;
        const int lane = tid & 63;
        const int lg   = lane >> 4;
        const int ln   = lane & 15;
        const int t0   = (blk * 4 + wave) * 16;

        bf16x8 a6[6];
        #pragma unroll
        for (int kk = 0; kk < 6; ++kk) {
            float v[8];
            #pragma unroll
            for (int j = 0; j < 8; ++j) v[j] = hs[ln * 193 + kk * 32 + lg * 8 + j];
            a6[kk] = pack8(v);
        }

        f32x4 acc = (f32x4){0.f, 0.f, 0.f, 0.f};
        #pragma unroll
        for (int kk = 0; kk < 6; ++kk) {
            float w[8];
            #pragma unroll
            for (int j = 0; j < 8; ++j)
                w[j] = W2[(size_t)(kk * 32 + lg * 8 + j) * TOTAL + t0 + ln];
            acc = __builtin_amdgcn_mfma_f32_16x16x32_bf16(a6[kk], pack8(w), acc, 0, 0, 0);
        }

        const int t    = t0 + ln;
        const float bias = b2[t];
        const int co  = t / KSZ;
        const int rem = t - co * KSZ;
        const int ci  = rem / 9;
        const int p9  = rem - ci * 9;
        const float idv = (p9 == 4 && co == ci) ? 1.f : 0.f;
        unsigned short* pA = Ag + (size_t)(p9 * 64 + co) * 64 + ci;
        #pragma unroll
        for (int rg = 0; rg < 4; ++rg) {
            const int bi = lg * 4 + rg;
            pA[(size_t)bi * TOTAL] = f2bf(tanhf(acc[rg] + bias) + idv);
        }
    }
}

// -------- K3: conv MFMA implicit GEMM, 2-row strips, wave = 1 row x 64 co --------
// 896 blocks = 16b x 56 strips; 128 thr / 2 waves. LDS: 4 rows x 114 x 64 B = 29184 B.
// ci as 2 serial halves from split-plane P (no fetch amplification). Slice swizzle
// sl = g ^ (cell&3), gload_lds linear dest / inverse-swizzled source (r12-validated:
// ~1 conflict-cycle per read). Each ds_read_b128 feeds 4 MFMAs (all 64 co).
__global__ __launch_bounds__(128, 2) void conv_kernel(const unsigned short* __restrict__ Ag,
                                                      const unsigned short* __restrict__ P,
                                                      float* __restrict__ out) {
    __shared__ __align__(16) char lds[4 * LROWB];   // 29184 B
    const int tid = threadIdx.x;
    // XCD-chunked swizzle: 112 consecutive logical blocks (= 2 batches) per XCD
    const int bid   = (blockIdx.x & 7) * 112 + (blockIdx.x >> 3);
    const int b     = bid / 56;
    const int strip = bid - b * 56;
    const int y0    = strip * 2;

    const int r    = tid >> 6;                      // output row 0/1
    const int lane = tid & 63;
    const int lg   = lane >> 4;
    const int ln   = lane & 15;

    const unsigned short* Ab = Ag + (size_t)b * 9 * 4096;

    f32x4 acc[4][7];
    #pragma unroll
    for (int ct = 0; ct < 4; ++ct)
        #pragma unroll
        for (int t = 0; t < 7; ++t) acc[ct][t] = (f32x4){0.f, 0.f, 0.f, 0.f};

    #pragma unroll
    for (int h = 0; h < 2; ++h) {
        if (h) __syncthreads();                      // half-0 compute done before overwrite
        // ---- stage half h: padded rows y0..y0+3, plane h, linear LDS dest ----
        const char* Pb = (const char*)P + ((size_t)(b * 2 + h) * PW + y0) * LROWB;
        #pragma unroll
        for (int k = 0; k < 15; ++k) {
            const int i = k * 128 + tid;             // chunk 0..1823
            if (i < NCH) {
                const int s    = i / (PW * 4);
                const int rem  = i - s * (PW * 4);
                const int cell = rem >> 2;
                const int sl   = rem & 3;
                const int g    = sl ^ (cell & 3);    // inverse swizzle on source
                GLOAD_LDS16(Pb + (size_t)s * LROWB + cell * CELLB + g * 16,
                            lds + (size_t)i * 16);
            }
        }
        asm volatile("s_waitcnt vmcnt(0)" ::: "memory");
        __builtin_amdgcn_s_barrier();
        __builtin_amdgcn_sched_barrier(0);

        // ---- compute half h ----
        #pragma unroll
        for (int p9 = 0; p9 < 9; ++p9) {
            const int kh = p9 / 3, kw = p9 - 3 * kh;
            bf16x8 af[4];
            #pragma unroll
            for (int ct = 0; ct < 4; ++ct)
                af[ct] = *(const bf16x8*)(Ab + (size_t)(p9 * 64 + ct * 16 + ln) * 64
                                          + h * 32 + lg * 8);
            const char* lbase = lds + (r + kh) * LROWB;
            #pragma unroll
            for (int t = 0; t < 7; ++t) {
                const int cell = ln + kw + 16 * t;
                const int sl   = lg ^ (cell & 3);
                const bf16x8 bf = *(const bf16x8*)(lbase + cell * CELLB + sl * 16);
                #pragma unroll
                for (int ct = 0; ct < 4; ++ct)
                    acc[ct][t] = __builtin_amdgcn_mfma_f32_16x16x32_bf16(af[ct], bf, acc[ct][t], 0, 0, 0);
            }
        }
    }

    // ---- epilogue: pure stores (residual folded into A) ----
    const int y = y0 + r;
    float* ob = out + (((size_t)b * COUT + lg * 4) * HH + y) * WW + ln;
    #pragma unroll
    for (int ct = 0; ct < 4; ++ct)
        #pragma unroll
        for (int t = 0; t < 7; ++t)
            #pragma unroll
            for (int rg = 0; rg < 4; ++rg)
                ob[((size_t)(ct * 16 + rg)) * HH * WW + t * 16] = acc[ct][t][rg];
}

extern "C" void kernel_launch(void* const* d_in, const int* in_sizes, int n_in,
                              void* d_out, int out_size, void* d_ws, size_t ws_size,
                              hipStream_t stream) {
    const float* cls      = (const float*)d_in[0];
    const float* features = (const float*)d_in[1];
    const float* W1       = (const float*)d_in[2];
    const float* b1       = (const float*)d_in[3];
    const float* W2       = (const float*)d_in[4];
    const float* b2       = (const float*)d_in[5];
    float* out = (float*)d_out;

    float*          h  = (float*)d_ws;                       // 12 KB
    unsigned short* Ag = (unsigned short*)(h + BB * HID);    // 1.18 MB bf16 A[b][p9][co][ci]
    unsigned short* P  = Ag + (size_t)BB * 9 * 4096;         // 26.6 MB split-plane NHWC bf16

    mlp1_kernel<<<192, 256, 0, stream>>>(cls, W1, b1, h);
    pre_mlp2<<<HH * BB + 32 + 576, 256, 0, stream>>>(features, P, h, W2, b2, Ag);
    conv_kernel<<<896, 128, 0, stream>>>(Ag, P, out);
}

// Round 14
// 62.898 us; speedup vs baseline: 1.3688x; 1.0716x over previous
//
#include <hip/hip_runtime.h>
#include <hip/hip_bf16.h>

#define BB   16
#define EMB  768
#define CIN  64
#define COUT 64
#define HH   112
#define WW   112
#define HID  192
#define TOTAL 36864                 // COUT*CIN*9
#define KSZ  576                    // CIN*9
#define PW   114                    // padded H/W
#define CELL 128                    // bytes per P cell: 64 ci * 2B
#define ROWB (PW * CELL)            // 14592 B per padded row

typedef short bf16x8 __attribute__((ext_vector_type(8)));
typedef float f32x4  __attribute__((ext_vector_type(4)));
typedef int   i32x4  __attribute__((ext_vector_type(4)));

static __device__ __forceinline__ unsigned short f2bf(float f) {
    unsigned u = __float_as_uint(f);
    u += 0x7FFF + ((u >> 16) & 1);          // RNE
    return (unsigned short)(u >> 16);
}

static __device__ __forceinline__ bf16x8 pack8(const float* v) {
    bf16x8 r;
    #pragma unroll
    for (int j = 0; j < 8; ++j) r[j] = (short)f2bf(v[j]);
    return r;
}

#define GLOAD_LDS16(g, l) \
    __builtin_amdgcn_global_load_lds((const __attribute__((address_space(1))) void*)(g), \
                                     (__attribute__((address_space(3))) void*)(l), 16, 0, 0)

// ---- K1: mlp1  h = relu(cls @ W1 + b1).  192 blocks = 16b x 12jg ----
__global__ __launch_bounds__(256) void mlp1_kernel(const float* __restrict__ cls,
                                                   const float* __restrict__ W1,
                                                   const float* __restrict__ b1,
                                                   float* __restrict__ h) {
    __shared__ float xs[EMB];
    __shared__ float red[16][17];
    const int b   = blockIdx.x / 12;
    const int jg  = blockIdx.x - 12 * b;
    const int tid = threadIdx.x;
    for (int i = tid; i < EMB; i += 256) xs[i] = cls[b * EMB + i];
    __syncthreads();
    const int j16 = tid & 15;
    const int kq  = tid >> 4;
    const int j   = jg * 16 + j16;
    float acc = 0.f;
    #pragma unroll
    for (int k = kq * 48; k < kq * 48 + 48; ++k) acc += xs[k] * W1[k * HID + j];
    red[j16][kq] = acc;
    __syncthreads();
    if (tid < 16) {
        float s = b1[jg * 16 + tid];
        #pragma unroll
        for (int q = 0; q < 16; ++q) s += red[tid][q];
        h[b * HID + jg * 16 + tid] = fmaxf(s, 0.f);
    }
}

// ---- K2: fused prepass (XCD-local P, full 64-ci cells) + mlp2 MFMA GEMM ----
// data-row blocks 0..1791 mapped so XCD x (= bid&7) writes batches {2x, 2x+1}:
//   b = (bid&7)*2 + ((bid>>3) >= 112),  y = (bid>>3) % 112
// matching conv's XCD swizzle -> conv stage reads hit the local L2.
__global__ __launch_bounds__(256) void pre_mlp2(const float* __restrict__ feat,
                                                unsigned short* __restrict__ P,
                                                const float* __restrict__ h,
                                                const float* __restrict__ W2,
                                                const float* __restrict__ b2,
                                                unsigned short* __restrict__ Ag) {
    __shared__ float hs[16 * 193];
    const int bid = blockIdx.x;
    const int tid = threadIdx.x;

    if (bid < HH * BB) {
        // ---------------- prepass data row ----------------
        const int j = bid >> 3;
        const int b = (bid & 7) * 2 + (j >= 112 ? 1 : 0);
        const int y = j - (j >= 112 ? 112 : 0);       // image row 0..111
        unsigned short* Prow = P + ((size_t)b * PW + y + 1) * (PW * 64);
        if (tid < 16) {                               // zero x-halo cells 0 and 113
            const int cell = (tid >> 3) ? (PW - 1) : 0;
            *(i32x4*)((char*)Prow + cell * CELL + (tid & 7) * 16) = (i32x4){0, 0, 0, 0};
        }
        const int o = tid >> 5;                       // ci octet 0..7
        const int q = tid & 31;                       // px quad, active < 28
        if (q < 28) {
            const float* fb = feat + (((size_t)b * CIN + o * 8) * HH + y) * WW + 4 * q;
            f32x4 v[8];
            #pragma unroll
            for (int j2 = 0; j2 < 8; ++j2) v[j2] = *(const f32x4*)(fb + (size_t)j2 * (HH * WW));
            #pragma unroll
            for (int i = 0; i < 4; ++i) {
                unsigned short w[8];
                #pragma unroll
                for (int j2 = 0; j2 < 8; ++j2) w[j2] = f2bf(v[j2][i]);
                *(bf16x8*)(Prow + (size_t)(4 * q + i + 1) * 64 + o * 8) = *(bf16x8*)w;
            }
        }
    } else if (bid < HH * BB + 32) {
        // ---------------- halo rows (py = 0, 113) ----------------
        const int idx = bid - HH * BB;
        const int b   = idx & 15;
        unsigned short* Prow = P + ((size_t)b * PW + ((idx >> 4) ? (PW - 1) : 0)) * (PW * 64);
        #pragma unroll
        for (int k = 0; k < 4; ++k) {
            const int i = tid + 256 * k;
            if (i < 912) ((i32x4*)Prow)[i] = (i32x4){0, 0, 0, 0};
        }
    } else {
        // ---------------- mlp2: params = tanh(h @ W2 + b2) + center identity ----------------
        const int blk = bid - (HH * BB + 32);         // 0..575
        for (int i = tid; i < BB * HID; i += 256) {
            const int bb = i / HID;
            hs[bb * 193 + (i - bb * HID)] = h[i];
        }
        __syncthreads();
        const int wave = tid >> 6;
        const int lane = tid & 63;
        const int lg   = lane >> 4;
        const int ln   = lane & 15;
        const int t0   = (blk * 4 + wave) * 16;

        bf16x8 a6[6];
        #pragma unroll
        for (int kk = 0; kk < 6; ++kk) {
            float v[8];
            #pragma unroll
            for (int j = 0; j < 8; ++j) v[j] = hs[ln * 193 + kk * 32 + lg * 8 + j];
            a6[kk] = pack8(v);
        }

        f32x4 acc = (f32x4){0.f, 0.f, 0.f, 0.f};
        #pragma unroll
        for (int kk = 0; kk < 6; ++kk) {
            float w[8];
            #pragma unroll
            for (int j = 0; j < 8; ++j)
                w[j] = W2[(size_t)(kk * 32 + lg * 8 + j) * TOTAL + t0 + ln];
            acc = __builtin_amdgcn_mfma_f32_16x16x32_bf16(a6[kk], pack8(w), acc, 0, 0, 0);
        }

        const int t    = t0 + ln;
        const float bias = b2[t];
        const int co  = t / KSZ;
        const int rem = t - co * KSZ;
        const int ci  = rem / 9;
        const int p9  = rem - ci * 9;
        const float idv = (p9 == 4 && co == ci) ? 1.f : 0.f;
        unsigned short* pA = Ag + (size_t)(p9 * 64 + co) * 64 + ci;
        #pragma unroll
        for (int rg = 0; rg < 4; ++rg) {
            const int bi = lg * 4 + rg;
            pA[(size_t)bi * TOTAL] = f2bf(tanhf(acc[rg] + bias) + idv);
        }
    }
}

// -------- K3: conv MFMA implicit GEMM: single stage, wave = 1 row x 64 co --------
// 896 blocks = 16b x 56 strips; 128 thr / 2 waves. LDS: 4 rows x 114 x 128 B = 58368 B
// (both ci planes staged ONCE -> one vmcnt(0)+barrier per block). Slice swizzle
// sl = g ^ (cell&7) on gload_lds source (linear dest); reads undo it -> 8 words/bank.
// Each ds_read_b128 feeds 4 MFMAs (all 64 co). A-frags loaded per-p9 (acc = 112 VGPR).
__global__ __launch_bounds__(128, 2) void conv_kernel(const unsigned short* __restrict__ Ag,
                                                      const unsigned short* __restrict__ P,
                                                      float* __restrict__ out) {
    __shared__ __align__(16) char lds[4 * ROWB];    // 58368 B
    const int tid = threadIdx.x;
    // XCD-chunked swizzle: XCD x owns 112 consecutive logical blocks = batches {2x,2x+1}
    const int bid   = (blockIdx.x & 7) * 112 + (blockIdx.x >> 3);
    const int b     = bid / 56;
    const int strip = bid - b * 56;
    const int y0    = strip * 2;

    const int r    = tid >> 6;                      // output row 0/1
    const int lane = tid & 63;
    const int lg   = lane >> 4;
    const int ln   = lane & 15;

    // ---- single stage: padded rows y0..y0+3, both planes, 3648 chunks ----
    const char* Pb = (const char*)P + ((size_t)b * PW + y0) * ROWB;
    #pragma unroll
    for (int k = 0; k < 28; ++k) {
        const int i = k * 128 + tid;                // chunk 0..3583
        const int s = i / 912;
        const int jj = i - s * 912;
        const int c = jj >> 3, g = jj & 7;
        GLOAD_LDS16(Pb + (size_t)s * ROWB + c * CELL + ((g ^ (c & 7)) << 4),
                    lds + (size_t)i * 16);
    }
    if (tid < 64) {                                 // chunks 3584..3647
        const int i = 3584 + tid;
        const int jj = i - 3 * 912;
        const int c = jj >> 3, g = jj & 7;
        GLOAD_LDS16(Pb + (size_t)3 * ROWB + c * CELL + ((g ^ (c & 7)) << 4),
                    lds + (size_t)i * 16);
    }

    const unsigned short* Ab = Ag + (size_t)b * 9 * 4096;

    f32x4 acc[4][7];
    #pragma unroll
    for (int ct = 0; ct < 4; ++ct)
        #pragma unroll
        for (int t = 0; t < 7; ++t) acc[ct][t] = (f32x4){0.f, 0.f, 0.f, 0.f};

    asm volatile("s_waitcnt vmcnt(0)" ::: "memory");
    __builtin_amdgcn_s_barrier();
    __builtin_amdgcn_sched_barrier(0);

    // ---- compute: both ci planes from the one staged tile ----
    #pragma unroll
    for (int cib = 0; cib < 2; ++cib) {
        #pragma unroll
        for (int p9 = 0; p9 < 9; ++p9) {
            const int kh = p9 / 3, kw = p9 - 3 * kh;
            bf16x8 af[4];
            #pragma unroll
            for (int ct = 0; ct < 4; ++ct)
                af[ct] = *(const bf16x8*)(Ab + (size_t)(p9 * 64 + ct * 16 + ln) * 64
                                          + cib * 32 + lg * 8);
            const char* lbase = lds + (r + kh) * ROWB + (ln + kw) * CELL;
            const int   sw    = (((cib * 4 + lg) ^ ((ln + kw) & 7)) << 4);
            #pragma unroll
            for (int t = 0; t < 7; ++t) {
                const bf16x8 bf = *(const bf16x8*)(lbase + t * (16 * CELL) + sw);
                #pragma unroll
                for (int ct = 0; ct < 4; ++ct)
                    acc[ct][t] = __builtin_amdgcn_mfma_f32_16x16x32_bf16(af[ct], bf, acc[ct][t], 0, 0, 0);
            }
        }
    }

    // ---- epilogue: pure stores (residual folded into A) ----
    const int y = y0 + r;
    float* ob = out + (((size_t)b * COUT + lg * 4) * HH + y) * WW + ln;
    #pragma unroll
    for (int ct = 0; ct < 4; ++ct)
        #pragma unroll
        for (int t = 0; t < 7; ++t)
            #pragma unroll
            for (int rg = 0; rg < 4; ++rg)
                ob[((size_t)(ct * 16 + rg)) * HH * WW + t * 16] = acc[ct][t][rg];
}

extern "C" void kernel_launch(void* const* d_in, const int* in_sizes, int n_in,
                              void* d_out, int out_size, void* d_ws, size_t ws_size,
                              hipStream_t stream) {
    const float* cls      = (const float*)d_in[0];
    const float* features = (const float*)d_in[1];
    const float* W1       = (const float*)d_in[2];
    const float* b1       = (const float*)d_in[3];
    const float* W2       = (const float*)d_in[4];
    const float* b2       = (const float*)d_in[5];
    float* out = (float*)d_out;

    float*          h  = (float*)d_ws;                       // 12 KB
    unsigned short* Ag = (unsigned short*)(h + BB * HID);    // 1.18 MB bf16 A[b][p9][co][ci]
    unsigned short* P  = Ag + (size_t)BB * 9 * 4096;         // 26.6 MB padded NHWC bf16

    mlp1_kernel<<<192, 256, 0, stream>>>(cls, W1, b1, h);
    pre_mlp2<<<HH * BB + 32 + 576, 256, 0, stream>>>(features, P, h, W2, b2, Ag);
    conv_kernel<<<896, 128, 0, stream>>>(Ag, P, out);
}